// Round 6
// baseline (155.375 us; speedup 1.0000x reference)
//
#include <hip/hip_runtime.h>
#include <math.h>

#define DEP   96
#define HEADS 96
#define BSZ   16
#define DIM   512
#define REL   128
#define RELP  129   // REL + nil

typedef __attribute__((ext_vector_type(8))) _Float16  half8;    // 8 fp16 (4 VGPRs)
typedef __attribute__((ext_vector_type(2))) __fp16    fp16x2;   // cvt_pkrtz return type
typedef __attribute__((ext_vector_type(4))) float     floatx4;

__device__ __forceinline__ unsigned short f2h(float x) {
    union { _Float16 h; unsigned short u; } c;
    c.h = (_Float16)x;                                   // v_cvt_f16_f32 (RNE)
    return c.u;
}
// two f32 -> packed 2xf16 in one v_cvt_pkrtz_f16_f32
__device__ __forceinline__ unsigned pk_f2h(float a, float b) {
    union { fp16x2 h; unsigned u; } c;
    c.h = __builtin_amdgcn_cvt_pkrtz(a, b);
    return c.u;
}
// packed fp16 add / relu (VOP3P)
__device__ __forceinline__ unsigned pk_add_h2(unsigned a, unsigned b) {
    unsigned r; asm("v_pk_add_f16 %0, %1, %2" : "=v"(r) : "v"(a), "v"(b)); return r;
}
__device__ __forceinline__ unsigned pk_max_h2(unsigned a, unsigned b) {
    unsigned r; asm("v_pk_max_f16 %0, %1, %2" : "=v"(r) : "v"(a), "v"(b)); return r;
}

#define PSS 72   // LDS row stride (fp16 elems): 144 B = 16B-aligned, ~2-way banks (free)

// ---------------------------------------------------------------------------
// Kernel A: projections via fp16 MFMA (R5 shape — 32x64 tiles, 768 blocks,
// 3 resident/CU; measured neutral-to-slightly-better, keep).
//   z=0: P1[m][n] = outs@Wt[:, :512]^T + bt   (f32 out)
//   z=1: P2H[m][n]= graph@Wt[:, 512:]^T       (fp16 out)
// First 32 blocks also cast Wp -> WpH as a prelude.
// ---------------------------------------------------------------------------
__global__ __launch_bounds__(256) void proj_kernel(
    const float* __restrict__ outs, const float* __restrict__ graph,
    const float* __restrict__ Wt, const float* __restrict__ bt,
    const float* __restrict__ Wp,
    float* __restrict__ P1, unsigned short* __restrict__ P2H,
    unsigned short* __restrict__ WpH)
{
    // ---- Wp f32 -> fp16 prelude: 32 blocks x 256 thr ----
    {
        const int fb = (blockIdx.z * gridDim.y + blockIdx.y) * gridDim.x + blockIdx.x;
        if (fb < 32) {
            const int c = fb * 256 + (int)threadIdx.x;       // 0..8191 chunks of 8
            float4 a = *(const float4*)(Wp + (size_t)c * 8);
            float4 b = *(const float4*)(Wp + (size_t)c * 8 + 4);
            uint4 o;
            o.x = pk_f2h(a.x, a.y); o.y = pk_f2h(a.z, a.w);
            o.z = pk_f2h(b.x, b.y); o.w = pk_f2h(b.z, b.w);
            *(uint4*)(WpH + (size_t)c * 8) = o;
        }
    }

    const int z = blockIdx.z;
    const float* A = z ? graph : outs;
    const int off  = z ? DIM : 0;
    const int row0 = blockIdx.y * 32;
    const int col0 = blockIdx.x * 64;

    __shared__ __align__(16) unsigned short As[32 * PSS];   // [m][k] fp16
    __shared__ __align__(16) unsigned short Ws[64 * PSS];   // [n][k] fp16

    const int tid  = threadIdx.x;
    const int lane = tid & 63;
    const int wv   = tid >> 6;          // 0..3
    const int ln15 = lane & 15;
    const int quad = lane >> 4;
    const int mh   = wv & 1;            // m-half: rows [16*mh, 16*mh+16)
    const int nh   = wv >> 1;           // n-half: cols [32*nh, 32*nh+32)

    floatx4 acc[2];
    acc[0] = (floatx4){0.f,0.f,0.f,0.f};
    acc[1] = (floatx4){0.f,0.f,0.f,0.f};

    for (int kt = 0; kt < DIM; kt += 64) {
        // A: f32 load + packed RTZ cast to fp16 LDS (1 slot/thread)
        {
            const int r  = tid >> 3;            // 0..31
            const int e8 = (tid & 7) * 8;
            const float* p = A + (size_t)(row0 + r) * DIM + kt + e8;
            float4 va = *(const float4*)p;
            float4 vb = *(const float4*)(p + 4);
            uint4 o;
            o.x = pk_f2h(va.x, va.y); o.y = pk_f2h(va.z, va.w);
            o.z = pk_f2h(vb.x, vb.y); o.w = pk_f2h(vb.z, vb.w);
            *(uint4*)&As[r * PSS + e8] = o;
        }
        // Wt: f32 load + cast (2 slots/thread)
        #pragma unroll
        for (int q = 0; q < 2; ++q) {
            const int slot = q*256 + tid;       // 0..511
            const int r  = slot >> 3;           // 0..63
            const int e8 = (slot & 7) * 8;
            const float* p = Wt + (size_t)(col0 + r) * (2*DIM) + off + kt + e8;
            float4 va = *(const float4*)p;
            float4 vb = *(const float4*)(p + 4);
            uint4 o;
            o.x = pk_f2h(va.x, va.y); o.y = pk_f2h(va.z, va.w);
            o.z = pk_f2h(vb.x, vb.y); o.w = pk_f2h(vb.z, vb.w);
            *(uint4*)&Ws[r * PSS + e8] = o;
        }
        __syncthreads();
        #pragma unroll
        for (int ks = 0; ks < 64; ks += 32) {
            half8 af = *(const half8*)&As[(mh*16 + ln15) * PSS + ks + quad*8];
            #pragma unroll
            for (int nt = 0; nt < 2; ++nt) {
                half8 bf8 = *(const half8*)&Ws[(nh*32 + nt*16 + ln15) * PSS + ks + quad*8];
                acc[nt] = __builtin_amdgcn_mfma_f32_16x16x32_f16(af, bf8, acc[nt], 0, 0, 0);
            }
        }
        __syncthreads();
    }

    #pragma unroll
    for (int nt = 0; nt < 2; ++nt) {
        #pragma unroll
        for (int reg = 0; reg < 4; ++reg) {
            const int m = row0 + mh*16 + quad*4 + reg;
            const int n = col0 + nh*32 + nt*16 + ln15;
            float v = acc[nt][reg];
            if (!z) P1[(size_t)m * DIM + n] = v + bt[n];
            else    P2H[(size_t)m * DIM + n] = f2h(v);
        }
    }
}

// ---------------------------------------------------------------------------
// Kernel B: fused pairwise relu + fp16-MFMA GEMM + log_softmax(129).
// R6: 512 threads / 8 waves per block (was 256/4). Counters R0-R5 stable at
// MfmaUtil 15 / VALU 25 / HBM 20 / Occupancy 28% -> latency-bound, all
// phase-level fixes null. This doubles resident waves: 4 blocks x 8 waves =
// 2048 thr/CU = 100% of wave slots, REQUIRES VGPR<=64 (acc halves to 24:
// each wave now owns 48m x 32n). K-loop structure otherwise identical.
// Per ks: 5 ds_reads + 6 MFMA per wave; staging ~3.5 slots/thread.
// ---------------------------------------------------------------------------
#define HSS 72
#define WSS 72

__global__ __launch_bounds__(512, 8) void fused_kernel(
    const float* __restrict__ P1, const unsigned short* __restrict__ P2H,
    const unsigned short* __restrict__ WpH, const float* __restrict__ bp,
    float* __restrict__ out)
{
    const int db = blockIdx.x;      // d*16 + b
    const int b  = db & 15;

    // arena: hs[96][HSS] + ws[128][WSS] fp16 during K-loop; 48x129 f32 outbuf
    // in the epilogue (24768 B <= 32256 B, region dead after last MFMA).
    __shared__ __align__(16) char arena[96*HSS*2 + 128*WSS*2];
    unsigned short* hs = (unsigned short*)arena;               // h tile  [m][k]
    unsigned short* ws = (unsigned short*)(arena + 96*HSS*2);  // Wp tile [n][k]
    float* outb = (float*)arena;                               // [48*129] epilogue

    __shared__ __align__(16) unsigned short drowH[DIM];     // dep row fp16
    __shared__ float pmx[96][4];     // softmax partials per (row, col-quarter)
    __shared__ float pl [96][4];
    __shared__ float lseS[96];       // per-row lse

    const int tid  = threadIdx.x;       // 0..511
    const int lane = tid & 63;
    const int wv   = tid >> 6;          // 0..7
    const int ln15 = lane & 15;
    const int quad = lane >> 4;
    const int mh   = wv & 1;            // row half:    [48*mh, 48*mh+48)
    const int nh   = wv >> 1;           // col quarter: [32*nh, 32*nh+32)

    // dep row f32 -> fp16 (one-time; 256 threads cover 512 elems)
    if (tid < 256) {
        float2 v = *(const float2*)(P1 + (size_t)db * DIM + tid*2);
        *(unsigned*)&drowH[tid*2] = pk_f2h(v.x, v.y);
    }
    __syncthreads();

    floatx4 acc[3][2];
    #pragma unroll
    for (int i = 0; i < 3; ++i)
        #pragma unroll
        for (int j = 0; j < 2; ++j) acc[i][j] = (floatx4){0.f,0.f,0.f,0.f};

    for (int kt = 0; kt < DIM; kt += 64) {
        // ---- stage hs[h][e] = fp16 relu(drow[e] + P2H[h,b,e]), 96x64 ----
        // 768 slots over 512 threads: slot tid (all) + slot 512+tid (tid<256)
        {
            const int h  = tid >> 3;             // 0..63
            const int e8 = (tid & 7) * 8;
            uint4 pv = *(const uint4*)(P2H + ((size_t)h * BSZ + b) * DIM + kt + e8);
            uint4 dv = *(const uint4*)&drowH[kt + e8];
            uint4 o;
            o.x = pk_max_h2(pk_add_h2(pv.x, dv.x), 0u);
            o.y = pk_max_h2(pk_add_h2(pv.y, dv.y), 0u);
            o.z = pk_max_h2(pk_add_h2(pv.z, dv.z), 0u);
            o.w = pk_max_h2(pk_add_h2(pv.w, dv.w), 0u);
            *(uint4*)&hs[h * HSS + e8] = o;
        }
        if (tid < 256) {
            const int slot = 512 + tid;
            const int h  = slot >> 3;            // 64..95
            const int e8 = (slot & 7) * 8;
            uint4 pv = *(const uint4*)(P2H + ((size_t)h * BSZ + b) * DIM + kt + e8);
            uint4 dv = *(const uint4*)&drowH[kt + e8];
            uint4 o;
            o.x = pk_max_h2(pk_add_h2(pv.x, dv.x), 0u);
            o.y = pk_max_h2(pk_add_h2(pv.y, dv.y), 0u);
            o.z = pk_max_h2(pk_add_h2(pv.z, dv.z), 0u);
            o.w = pk_max_h2(pk_add_h2(pv.w, dv.w), 0u);
            *(uint4*)&hs[h * HSS + e8] = o;
        }
        // ---- stage ws[r][e] = WpH[r][kt+e], 128x64 (2 slots/thread) ----
        #pragma unroll
        for (int q = 0; q < 2; ++q) {
            const int slot = q*512 + tid;        // 0..1023
            const int r = slot >> 3;
            const int g = (slot & 7) * 8;
            *(uint4*)&ws[r * WSS + g] =
                *(const uint4*)(WpH + (size_t)r * DIM + kt + g);
        }
        __syncthreads();

        #pragma unroll
        for (int ks = 0; ks < 64; ks += 32) {
            half8 af[3], bf[2];
            #pragma unroll
            for (int mt = 0; mt < 3; ++mt)
                af[mt] = *(const half8*)&hs[(mh*48 + mt*16 + ln15) * HSS + ks + quad*8];
            #pragma unroll
            for (int nt = 0; nt < 2; ++nt)
                bf[nt] = *(const half8*)&ws[(nh*32 + nt*16 + ln15) * WSS + ks + quad*8];
            #pragma unroll
            for (int nt = 0; nt < 2; ++nt)
                #pragma unroll
                for (int mt = 0; mt < 3; ++mt)
                    acc[mt][nt] = __builtin_amdgcn_mfma_f32_16x16x32_f16(
                        af[mt], bf[nt], acc[mt][nt], 0, 0, 0);
        }
        __syncthreads();
    }

    // ---- epilogue phase 1: per-quarter softmax partials (no nil yet) ----
    float bpv[2];
    #pragma unroll
    for (int nt = 0; nt < 2; ++nt) bpv[nt] = bp[nh*32 + nt*16 + ln15];

    #pragma unroll
    for (int mt = 0; mt < 3; ++mt) {
        #pragma unroll
        for (int reg = 0; reg < 4; ++reg) {
            const int m = mh*48 + mt*16 + quad*4 + reg;
            float s[2];
            #pragma unroll
            for (int nt = 0; nt < 2; ++nt) s[nt] = acc[mt][nt][reg] + bpv[nt];
            float mx = fmaxf(s[0], s[1]);
            #pragma unroll
            for (int msk = 1; msk < 16; msk <<= 1) mx = fmaxf(mx, __shfl_xor(mx, msk));
            float l = 0.f;
            #pragma unroll
            for (int nt = 0; nt < 2; ++nt) l += __expf(s[nt] - mx);
            #pragma unroll
            for (int msk = 1; msk < 16; msk <<= 1) l += __shfl_xor(l, msk);
            if (ln15 == 0) { pmx[m][nh] = mx; pl[m][nh] = l; }
        }
    }
    __syncthreads();

    // ---- phase 1.5: lse once per row (combine 4 quarters + nil) ----
    if (tid < 96) {
        float mxq[4], lq[4];
        #pragma unroll
        for (int q = 0; q < 4; ++q) { mxq[q] = pmx[tid][q]; lq[q] = pl[tid][q]; }
        float MX = fmaxf(fmaxf(mxq[0], mxq[1]), fmaxf(mxq[2], mxq[3]));
        MX = fmaxf(MX, 0.f);                              // nil = 0 in max
        float L = __expf(-MX);                            // nil term
        #pragma unroll
        for (int q = 0; q < 4; ++q) L += lq[q] * __expf(mxq[q] - MX);
        lseS[tid] = MX + __logf(L);
    }
    __syncthreads();

    // ---- phase 2: stage each 48-row half in LDS, stream out coalesced ----
    #pragma unroll
    for (int g = 0; g < 2; ++g) {
        if (mh == g) {
            #pragma unroll
            for (int mt = 0; mt < 3; ++mt) {
                #pragma unroll
                for (int reg = 0; reg < 4; ++reg) {
                    const int lrow = mt*16 + quad*4 + reg;      // 0..47
                    const float lse = lseS[g*48 + lrow];
                    #pragma unroll
                    for (int nt = 0; nt < 2; ++nt)
                        outb[lrow*RELP + 1 + nh*32 + nt*16 + ln15] =
                            acc[mt][nt][reg] + bpv[nt] - lse;
                    if (nh == 0 && ln15 == 0) outb[lrow*RELP] = -lse;
                }
            }
        }
        __syncthreads();
        // 48*129 = 6192 floats = 1548 float4, contiguous in out
        float4* gout = (float4*)(out + (size_t)db * (HEADS*RELP) + g * (48*RELP));
        const float4* lsrc = (const float4*)outb;
        for (int j = tid; j < 1548; j += 512)
            gout[j] = lsrc[j];
        __syncthreads();
    }
}

extern "C" void kernel_launch(void* const* d_in, const int* in_sizes, int n_in,
                              void* d_out, int out_size, void* d_ws, size_t ws_size,
                              hipStream_t stream) {
    const float* outs  = (const float*)d_in[0];
    const float* graph = (const float*)d_in[1];
    const float* Wt    = (const float*)d_in[2];
    const float* bt    = (const float*)d_in[3];
    const float* Wp    = (const float*)d_in[4];
    const float* bp    = (const float*)d_in[5];
    float* out = (float*)d_out;

    // Workspace: 4,849,664 B (WtH eliminated; Wt cast inline in proj).
    float* P1           = (float*)d_ws;                     // [1536][512] f32   (3 MB)
    unsigned short* P2H = (unsigned short*)(P1 + 786432);   // [1536][512] fp16  (1.5 MB)
    unsigned short* WpH = P2H + 786432;                     // [128][512]  fp16  (128 KB)

    proj_kernel<<<dim3(DIM/64, (DEP*BSZ)/32, 2), 256, 0, stream>>>(
        outs, graph, Wt, bt, Wp, P1, P2H, WpH);
    fused_kernel<<<DEP*BSZ, 512, 0, stream>>>(P1, P2H, WpH, bp, out);
}